// Round 20
// baseline (215.362 us; speedup 1.0000x reference)
//
#include <hip/hip_runtime.h>
#include <hip/hip_bf16.h>
#include <stdint.h>
#include <stddef.h>

#define Bb 256
#define Mm 128
#define Ee 512
#define Vv 32000
#define E3 1536

typedef __attribute__((ext_vector_type(8))) short bf16x8;
typedef __attribute__((ext_vector_type(4))) float f32x4;

__device__ __forceinline__ float bf2f(unsigned short u) {
  union { unsigned int i; float f; } v; v.i = ((unsigned int)u) << 16; return v.f;
}
__device__ __forceinline__ unsigned int f2bf(float f) {
  union { float f; unsigned int u; } v; v.f = f;
  unsigned int u = v.u;
  return ((u + 0x7fffu + ((u >> 16) & 1u)) >> 16);
}

// in2 stored in MFMA-fragment order: unit (mblk = row>>4, kb = col>>5) of 512
// bf16; within unit, lane = (row&15) + ((col>>3)&3)*16 holds 8 elems (col&7).
#define IN2F_IDX(bb, col)                                                     \
  ((((size_t)((bb) >> 4) * 32 + ((col) >> 5)) * 512) +                        \
   (size_t)((((bb) & 15) + (((col) >> 3) & 3) * 16) * 8 + ((col) & 7)))

// 3 fp32 tables -> 3 bf16 tables, concat [t][V][E].
__global__ void convert_kernel(const float* __restrict__ A0, const float* __restrict__ A1,
                               const float* __restrict__ A2,
                               unsigned short* __restrict__ tabB) {
  const int t = blockIdx.y;
  const float* src = (t == 0) ? A0 : (t == 1) ? A1 : A2;
  unsigned short* dst = tabB + (size_t)t * Vv * Ee;
  const int n4 = Vv * Ee / 4;
  for (int i = blockIdx.x * blockDim.x + threadIdx.x; i < n4; i += gridDim.x * blockDim.x) {
    f32x4 v = __builtin_nontemporal_load((const f32x4*)src + i);
    unsigned int o0 = f2bf(v.x) | (f2bf(v.y) << 16);
    unsigned int o1 = f2bf(v.z) | (f2bf(v.w) << 16);
    ((uint2*)dst)[i] = make_uint2(o0, o1);
  }
}

// gi = A1[y_] @ W_ih^T (z=0), gh = h @ W_hh^T (z=1); fp32 tiled GEMM 64x64, BK=16
__global__ void gru_gemm_kernel(const int* __restrict__ y,
                                const float* __restrict__ A1,
                                const float* __restrict__ hprev,
                                const float* __restrict__ W_ih,
                                const float* __restrict__ W_hh,
                                float* __restrict__ gi,
                                float* __restrict__ gh) {
  const int z = blockIdx.z;
  const float* W = z ? W_hh : W_ih;
  float* C = z ? gh : gi;
  const int by = blockIdx.x * 64;
  const int jy = blockIdx.y * 64;
  __shared__ float As[16][65];
  __shared__ float Bs[16][65];
  const int tx = threadIdx.x & 15, ty = threadIdx.x >> 4;
  float acc[4][4] = {};
  for (int k0 = 0; k0 < Ee; k0 += 16) {
#pragma unroll
    for (int it = 0; it < 4; ++it) {
      int r = ty + it * 16;
      int row = by + r;
      const float* arow = z ? (hprev + (size_t)row * Ee) : (A1 + (size_t)y[row] * Ee);
      As[tx][r] = arow[k0 + tx];
      Bs[tx][r] = W[(size_t)(jy + r) * Ee + k0 + tx];
    }
    __syncthreads();
#pragma unroll
    for (int kk = 0; kk < 16; ++kk) {
      float a[4], bb[4];
#pragma unroll
      for (int i = 0; i < 4; ++i) { a[i] = As[kk][ty * 4 + i]; bb[i] = Bs[kk][tx * 4 + i]; }
#pragma unroll
      for (int i = 0; i < 4; ++i)
#pragma unroll
        for (int j = 0; j < 4; ++j)
          acc[i][j] += a[i] * bb[j];
    }
    __syncthreads();
  }
#pragma unroll
  for (int i = 0; i < 4; ++i)
#pragma unroll
    for (int j = 0; j < 4; ++j)
      C[(size_t)(by + ty * 4 + i) * E3 + jy + tx * 4 + j] = acc[i][j];
}

// Fused: gather (bf16/fp32 tables -> LDS bf16, wave-per-row coalesced) + GRU gates + 3 hops.
__global__ __launch_bounds__(1024) void fused_kernel(
    const int* __restrict__ ctx,
    const unsigned short* __restrict__ tabB,
    const float* __restrict__ A0, const float* __restrict__ A1,
    const float* __restrict__ A2,
    const float* __restrict__ gi, const float* __restrict__ gh,
    const float* __restrict__ b_ih, const float* __restrict__ b_hh,
    const float* __restrict__ h0,
    float* __restrict__ out_h, unsigned short* __restrict__ in2f,
    float* __restrict__ p_out) {
  extern __shared__ char smem[];
  unsigned short* Vlds = (unsigned short*)smem;        // [128][512] bf16 = 128KB
  float* p_lds = (float*)(smem + 131072);              // [128]
  float* qbuf = (float*)(smem + 131584);               // [512]
  float* obuf = (float*)(smem + 133632);               // [4][512]

  const int b = blockIdx.x;
  const int tid = threadIdx.x;
  const int lane = tid & 63, w = tid >> 6;  // 16 waves

  if (tid < 512) {
    const int e = tid;
    const float* gib = gi + (size_t)b * E3;
    const float* ghb = gh + (size_t)b * E3;
    float ir = gib[e] + b_ih[e];
    float iz = gib[512 + e] + b_ih[512 + e];
    float inn = gib[1024 + e] + b_ih[1024 + e];
    float hr = ghb[e] + b_hh[e];
    float hz = ghb[512 + e] + b_hh[512 + e];
    float hn = ghb[1024 + e] + b_hh[1024 + e];
    float r = 1.f / (1.f + __expf(-(ir + hr)));
    float z = 1.f / (1.f + __expf(-(iz + hz)));
    float n = tanhf(inn + r * hn);
    float hp = h0[(size_t)b * Ee + e];
    float hnew = (1.f - z) * n + z * hp;
    out_h[(size_t)b * Ee + e] = hnew;
    in2f[IN2F_IDX(b, e)] = (unsigned short)f2bf(hnew);
    qbuf[e] = hnew;
  }

#define GATHER_B(T)                                                          \
  {                                                                          \
    const unsigned short* Tb = tabB + (size_t)(T) * ((size_t)Vv * Ee);       \
    _Pragma("unroll 2")                                                      \
    for (int r8 = 0; r8 < 8; ++r8) {                                         \
      const int row = w * 8 + r8;                                            \
      const int4 cc = *(const int4*)(ctx + ((size_t)b * Mm + row) * 4);      \
      uint4 va = *(const uint4*)(Tb + (size_t)cc.x * Ee + lane * 8);         \
      uint4 vb = *(const uint4*)(Tb + (size_t)cc.y * Ee + lane * 8);         \
      uint4 vc = *(const uint4*)(Tb + (size_t)cc.z * Ee + lane * 8);         \
      uint4 vd = *(const uint4*)(Tb + (size_t)cc.w * Ee + lane * 8);         \
      const unsigned int* pa = (const unsigned int*)&va;                     \
      const unsigned int* pb = (const unsigned int*)&vb;                     \
      const unsigned int* pc = (const unsigned int*)&vc;                     \
      const unsigned int* pd = (const unsigned int*)&vd;                     \
      unsigned int o[4];                                                     \
      _Pragma("unroll")                                                      \
      for (int j = 0; j < 4; ++j) {                                          \
        float lo = bf2f((unsigned short)(pa[j] & 0xffff)) +                  \
                   bf2f((unsigned short)(pb[j] & 0xffff)) +                  \
                   bf2f((unsigned short)(pc[j] & 0xffff)) +                  \
                   bf2f((unsigned short)(pd[j] & 0xffff));                   \
        float hi = bf2f((unsigned short)(pa[j] >> 16)) +                     \
                   bf2f((unsigned short)(pb[j] >> 16)) +                     \
                   bf2f((unsigned short)(pc[j] >> 16)) +                     \
                   bf2f((unsigned short)(pd[j] >> 16));                      \
        o[j] = f2bf(lo) | (f2bf(hi) << 16);                                  \
      }                                                                      \
      *(uint4*)(Vlds + (size_t)row * Ee + lane * 8) = *(uint4*)o;            \
    }                                                                        \
  }

#define GATHER_F(TAB)                                                        \
  {                                                                          \
    _Pragma("unroll 2")                                                      \
    for (int r8 = 0; r8 < 8; ++r8) {                                         \
      const int row = w * 8 + r8;                                            \
      const int4 cc = *(const int4*)(ctx + ((size_t)b * Mm + row) * 4);      \
      const float* s0 = TAB + (size_t)cc.x * Ee + lane * 8;                  \
      const float* s1 = TAB + (size_t)cc.y * Ee + lane * 8;                  \
      const float* s2 = TAB + (size_t)cc.z * Ee + lane * 8;                  \
      const float* s3 = TAB + (size_t)cc.w * Ee + lane * 8;                  \
      float4 a0 = *(const float4*)s0, a1 = *(const float4*)(s0 + 4);         \
      float4 b0 = *(const float4*)s1, b1 = *(const float4*)(s1 + 4);         \
      float4 c0 = *(const float4*)s2, c1 = *(const float4*)(s2 + 4);         \
      float4 d0 = *(const float4*)s3, d1 = *(const float4*)(s3 + 4);         \
      unsigned int o[4];                                                     \
      o[0] = f2bf(a0.x + b0.x + c0.x + d0.x) |                               \
             (f2bf(a0.y + b0.y + c0.y + d0.y) << 16);                        \
      o[1] = f2bf(a0.z + b0.z + c0.z + d0.z) |                               \
             (f2bf(a0.w + b0.w + c0.w + d0.w) << 16);                        \
      o[2] = f2bf(a1.x + b1.x + c1.x + d1.x) |                               \
             (f2bf(a1.y + b1.y + c1.y + d1.y) << 16);                        \
      o[3] = f2bf(a1.z + b1.z + c1.z + d1.z) |                               \
             (f2bf(a1.w + b1.w + c1.w + d1.w) << 16);                        \
      *(uint4*)(Vlds + (size_t)row * Ee + lane * 8) = *(uint4*)o;            \
    }                                                                        \
  }

#define GATHER(T, TAB) { if (tabB) GATHER_B(T) else GATHER_F(TAB) }

#define SCORE_PHASE(EMIT)                                                    \
  {                                                                          \
    float qf[8];                                                             \
    *(float4*)&qf[0] = *(const float4*)&qbuf[lane * 8];                      \
    *(float4*)&qf[4] = *(const float4*)&qbuf[lane * 8 + 4];                  \
    _Pragma("unroll")                                                        \
    for (int r = 0; r < 8; ++r) {                                            \
      const int m = w * 8 + r;                                               \
      uint4 kv = *(const uint4*)(Vlds + (size_t)m * Ee + lane * 8);          \
      const unsigned int* p4 = (const unsigned int*)&kv;                     \
      float s = 0.f;                                                         \
      _Pragma("unroll")                                                      \
      for (int x = 0; x < 4; ++x) {                                          \
        s += bf2f((unsigned short)(p4[x] & 0xffff)) * qf[2 * x];             \
        s += bf2f((unsigned short)(p4[x] >> 16)) * qf[2 * x + 1];            \
      }                                                                      \
      _Pragma("unroll")                                                      \
      for (int off = 32; off > 0; off >>= 1) s += __shfl_down(s, off);       \
      if (lane == 0) { EMIT; }                                               \
    }                                                                        \
  }

#define SOFTMAX_PHASE                                                        \
  if (tid < 64) {                                                            \
    float v0 = p_lds[tid], v1 = p_lds[tid + 64];                             \
    float mx = fmaxf(v0, v1);                                                \
    _Pragma("unroll")                                                        \
    for (int off = 32; off > 0; off >>= 1) mx = fmaxf(mx, __shfl_xor(mx, off)); \
    float e0 = __expf(v0 - mx), e1 = __expf(v1 - mx);                        \
    float s = e0 + e1;                                                       \
    _Pragma("unroll")                                                        \
    for (int off = 32; off > 0; off >>= 1) s += __shfl_xor(s, off);          \
    float inv = 1.f / s;                                                     \
    p_lds[tid] = e0 * inv;                                                   \
    p_lds[tid + 64] = e1 * inv;                                              \
  }

#define O_PHASE                                                              \
  {                                                                          \
    const int g = tid >> 8, t = tid & 255;                                   \
    const int e2 = t * 2;                                                    \
    float a0 = 0.f, a1 = 0.f;                                                \
    _Pragma("unroll 4")                                                      \
    for (int m = g * 32; m < g * 32 + 32; ++m) {                             \
      unsigned int vv = *(const unsigned int*)(Vlds + (size_t)m * Ee + e2);  \
      float ww = p_lds[m];                                                   \
      a0 += ww * bf2f((unsigned short)(vv & 0xffff));                        \
      a1 += ww * bf2f((unsigned short)(vv >> 16));                           \
    }                                                                        \
    obuf[g * 512 + e2] = a0;                                                 \
    obuf[g * 512 + e2 + 1] = a1;                                             \
  }

  // ---- hop 0
  GATHER(0, A0)
  __syncthreads();
  SCORE_PHASE(p_lds[m] = s)
  __syncthreads();
  SOFTMAX_PHASE
  GATHER(1, A1)
  __syncthreads();
  O_PHASE
  __syncthreads();
  if (tid < 512) {
    const int e = tid;
    float o = obuf[e] + obuf[512 + e] + obuf[1024 + e] + obuf[1536 + e];
    qbuf[e] = qbuf[e] + o;
    in2f[IN2F_IDX(b, 512 + e)] = (unsigned short)f2bf(o);
  }
  __syncthreads();

  // ---- hop 1
  SCORE_PHASE(p_lds[m] = s)
  __syncthreads();
  SOFTMAX_PHASE
  GATHER(2, A2)
  __syncthreads();
  O_PHASE
  __syncthreads();
  if (tid < 512) {
    const int e = tid;
    qbuf[e] = qbuf[e] + obuf[e] + obuf[512 + e] + obuf[1024 + e] + obuf[1536 + e];
  }
  __syncthreads();

  // ---- hop 2
  SCORE_PHASE(p_out[b * Mm + m] = s)
}

// p_vocab = in2f(bf16, fragment-order) @ lin_W^T + lin_b.
// Grid = 500 N-tiles of 64, full M=256 per block -> W fetched exactly once.
// NEW vs R19: fix the W DRAM GRANULE. All prior variants read W in 256B
// row-slices at 4KB stride per k-step (strided pattern -> ~1.8 TB/s wall).
// Now: stage the ENTIRE 64x1024 W tile ONCE as a flat contiguous 256KB
// stream (1KB per wave-instr), converting to a 128KB swizzled bf16 LDS tile
// (phys unit = u ^ (row&15) -> <=2-way reads). Single barrier, then a
// BARRIER-FREE K-loop: A reg-prefetched 2-deep (wave-private), W from
// read-only LDS; compiler pipelines freely. 1 block/CU, pure stream.
__global__ __launch_bounds__(1024) void pvocab_kernel(
    const unsigned short* __restrict__ in2f,
    const float* __restrict__ lin_W,
    const float* __restrict__ lin_b,
    float* __restrict__ out_pv) {
  __shared__ __align__(16) unsigned short Ws[64][1024];  // 128KB, swizzled units

  const int v0 = blockIdx.x * 64;
  const int tid = threadIdx.x;
  const int lane = tid & 63, w = tid >> 6;     // 16 waves, wave w -> mblk w
  const int l15 = lane & 15, lg = lane >> 4;

  // ---- stage whole W tile: flat contiguous read, convert, swizzled LDS write
  {
    const float* wsrc = lin_W + (size_t)v0 * 1024;
#pragma unroll
    for (int it = 0; it < 16; ++it) {
      int g = tid + it * 1024;          // float4-granule id, 0..16383
      int row = g >> 8;                 // 256 granules per row
      int c4 = g & 255;
      float4 v = *(const float4*)(wsrc + ((size_t)row * 1024 + c4 * 4));
      unsigned int o0 = f2bf(v.x) | (f2bf(v.y) << 16);
      unsigned int o1 = f2bf(v.z) | (f2bf(v.w) << 16);
      int u = c4 >> 1, h = c4 & 1;
      int up = u ^ (row & 15);
      *(uint2*)((char*)&Ws[0][0] + (size_t)row * 2048 + up * 16 + h * 8) =
          make_uint2(o0, o1);
    }
  }
  __syncthreads();

  f32x4 acc[4];
#pragma unroll
  for (int j = 0; j < 4; ++j) acc[j] = (f32x4){0.f, 0.f, 0.f, 0.f};

  const unsigned short* a_base = in2f + ((size_t)w * 32) * 512 + lane * 8;

  uint4 aA = *(const uint4*)(a_base);
  uint4 aB = *(const uint4*)(a_base + 512);

#define PV_KSTEP(BUF, KB)                                                    \
  {                                                                          \
    bf16x8 af = *(bf16x8*)&BUF;                                              \
    _Pragma("unroll")                                                        \
    for (int nf = 0; nf < 4; ++nf) {                                         \
      int row = nf * 16 + l15;                                               \
      int up = ((KB) * 4 + lg) ^ (row & 15);                                 \
      bf16x8 wf = *(const bf16x8*)((const char*)&Ws[0][0] +                  \
                                   (size_t)row * 2048 + up * 16);            \
      acc[nf] = __builtin_amdgcn_mfma_f32_16x16x32_bf16(af, wf, acc[nf], 0, 0, 0); \
    }                                                                        \
  }

#pragma unroll
  for (int kp = 0; kp < 16; ++kp) {
    PV_KSTEP(aA, 2 * kp)
    if (kp + 1 < 16) aA = *(const uint4*)(a_base + (size_t)(2 * kp + 2) * 512);
    PV_KSTEP(aB, 2 * kp + 1)
    if (kp + 1 < 16) aB = *(const uint4*)(a_base + (size_t)(2 * kp + 3) * 512);
  }

  {
#pragma unroll
    for (int nf = 0; nf < 4; ++nf) {
      int v = v0 + nf * 16 + l15;
      float bias = lin_b[v];
      int brow = w * 16 + lg * 4;
#pragma unroll
      for (int rr = 0; rr < 4; ++rr)
        out_pv[(size_t)(brow + rr) * Vv + v] = acc[nf][rr] + bias;
    }
  }
}

extern "C" void kernel_launch(void* const* d_in, const int* in_sizes, int n_in,
                              void* d_out, int out_size, void* d_ws, size_t ws_size,
                              hipStream_t stream) {
  const int* ctx = (const int*)d_in[0];
  const int* y = (const int*)d_in[1];
  const float* h0 = (const float*)d_in[2];
  const float* A0 = (const float*)d_in[3];
  const float* A1 = (const float*)d_in[4];
  const float* A2 = (const float*)d_in[5];
  // d_in[6] (C2) dead: memories[3] only feeds hop-2's o/q, which never reach an output
  const float* W_ih = (const float*)d_in[7];
  const float* W_hh = (const float*)d_in[8];
  const float* b_ih = (const float*)d_in[9];
  const float* b_hh = (const float*)d_in[10];
  const float* lin_W = (const float*)d_in[11];
  const float* lin_b = (const float*)d_in[12];

  const size_t tabBytes = (size_t)3 * Vv * Ee * 2;   // 98.3 MB
  const size_t giBytes = (size_t)Bb * E3 * 4;
  const size_t in2Bytes = (size_t)Bb * 1024 * 2;
  const bool bf16path = ws_size >= tabBytes + 2 * giBytes + in2Bytes;

  char* ws = (char*)d_ws;
  size_t off = 0;
  unsigned short* tabB = nullptr;
  if (bf16path) { tabB = (unsigned short*)ws; off += tabBytes; }
  float* gi = (float*)(ws + off); off += giBytes;
  float* gh = (float*)(ws + off); off += giBytes;
  unsigned short* in2f = (unsigned short*)(ws + off);

  float* out = (float*)d_out;
  float* p_ptr = out;                              // [B,M]
  float* p_voc = out + Bb * Mm;                    // [B,V]
  float* out_h = out + Bb * Mm + (size_t)Bb * Vv;  // [1,B,E]

  if (bf16path)
    convert_kernel<<<dim3(4096, 3), 256, 0, stream>>>(A0, A1, A2, tabB);
  gru_gemm_kernel<<<dim3(4, 24, 2), 256, 0, stream>>>(y, A1, h0, W_ih, W_hh, gi, gh);
  hipFuncSetAttribute((const void*)fused_kernel,
                      hipFuncAttributeMaxDynamicSharedMemorySize, 141824);
  fused_kernel<<<Bb, 1024, 141824, stream>>>(ctx, tabB, A0, A1, A2, gi, gh,
                                             b_ih, b_hh, h0, out_h, in2f, p_ptr);
  pvocab_kernel<<<Vv / 64, 1024, 0, stream>>>(in2f, lin_W, lin_b, p_voc);
}

// Round 21
// 210.209 us; speedup vs baseline: 1.0245x; 1.0245x over previous
//
#include <hip/hip_runtime.h>
#include <hip/hip_bf16.h>
#include <stdint.h>
#include <stddef.h>

#define Bb 256
#define Mm 128
#define Ee 512
#define Vv 32000
#define E3 1536

typedef __attribute__((ext_vector_type(8))) short bf16x8;
typedef __attribute__((ext_vector_type(4))) float f32x4;

__device__ __forceinline__ float bf2f(unsigned short u) {
  union { unsigned int i; float f; } v; v.i = ((unsigned int)u) << 16; return v.f;
}
__device__ __forceinline__ unsigned int f2bf(float f) {
  union { float f; unsigned int u; } v; v.f = f;
  unsigned int u = v.u;
  return ((u + 0x7fffu + ((u >> 16) & 1u)) >> 16);
}

// in2 stored in MFMA-fragment order: unit (mblk = row>>4, kb = col>>5) of 512
// bf16; within unit, lane = (row&15) + ((col>>3)&3)*16 holds 8 elems (col&7).
#define IN2F_IDX(bb, col)                                                     \
  ((((size_t)((bb) >> 4) * 32 + ((col) >> 5)) * 512) +                        \
   (size_t)((((bb) & 15) + (((col) >> 3) & 3) * 16) * 8 + ((col) & 7)))

// 3 fp32 tables -> 3 bf16 tables, concat [t][V][E].
__global__ void convert_kernel(const float* __restrict__ A0, const float* __restrict__ A1,
                               const float* __restrict__ A2,
                               unsigned short* __restrict__ tabB) {
  const int t = blockIdx.y;
  const float* src = (t == 0) ? A0 : (t == 1) ? A1 : A2;
  unsigned short* dst = tabB + (size_t)t * Vv * Ee;
  const int n4 = Vv * Ee / 4;
  for (int i = blockIdx.x * blockDim.x + threadIdx.x; i < n4; i += gridDim.x * blockDim.x) {
    f32x4 v = __builtin_nontemporal_load((const f32x4*)src + i);
    unsigned int o0 = f2bf(v.x) | (f2bf(v.y) << 16);
    unsigned int o1 = f2bf(v.z) | (f2bf(v.w) << 16);
    ((uint2*)dst)[i] = make_uint2(o0, o1);
  }
}

// gi = A1[y_] @ W_ih^T (z=0), gh = h @ W_hh^T (z=1); fp32 tiled GEMM 64x64, BK=16
__global__ void gru_gemm_kernel(const int* __restrict__ y,
                                const float* __restrict__ A1,
                                const float* __restrict__ hprev,
                                const float* __restrict__ W_ih,
                                const float* __restrict__ W_hh,
                                float* __restrict__ gi,
                                float* __restrict__ gh) {
  const int z = blockIdx.z;
  const float* W = z ? W_hh : W_ih;
  float* C = z ? gh : gi;
  const int by = blockIdx.x * 64;
  const int jy = blockIdx.y * 64;
  __shared__ float As[16][65];
  __shared__ float Bs[16][65];
  const int tx = threadIdx.x & 15, ty = threadIdx.x >> 4;
  float acc[4][4] = {};
  for (int k0 = 0; k0 < Ee; k0 += 16) {
#pragma unroll
    for (int it = 0; it < 4; ++it) {
      int r = ty + it * 16;
      int row = by + r;
      const float* arow = z ? (hprev + (size_t)row * Ee) : (A1 + (size_t)y[row] * Ee);
      As[tx][r] = arow[k0 + tx];
      Bs[tx][r] = W[(size_t)(jy + r) * Ee + k0 + tx];
    }
    __syncthreads();
#pragma unroll
    for (int kk = 0; kk < 16; ++kk) {
      float a[4], bb[4];
#pragma unroll
      for (int i = 0; i < 4; ++i) { a[i] = As[kk][ty * 4 + i]; bb[i] = Bs[kk][tx * 4 + i]; }
#pragma unroll
      for (int i = 0; i < 4; ++i)
#pragma unroll
        for (int j = 0; j < 4; ++j)
          acc[i][j] += a[i] * bb[j];
    }
    __syncthreads();
  }
#pragma unroll
  for (int i = 0; i < 4; ++i)
#pragma unroll
    for (int j = 0; j < 4; ++j)
      C[(size_t)(by + ty * 4 + i) * E3 + jy + tx * 4 + j] = acc[i][j];
}

// Fused: gather (bf16/fp32 tables -> LDS bf16, wave-per-row coalesced) + GRU gates + 3 hops.
__global__ __launch_bounds__(1024) void fused_kernel(
    const int* __restrict__ ctx,
    const unsigned short* __restrict__ tabB,
    const float* __restrict__ A0, const float* __restrict__ A1,
    const float* __restrict__ A2,
    const float* __restrict__ gi, const float* __restrict__ gh,
    const float* __restrict__ b_ih, const float* __restrict__ b_hh,
    const float* __restrict__ h0,
    float* __restrict__ out_h, unsigned short* __restrict__ in2f,
    float* __restrict__ p_out) {
  extern __shared__ char smem[];
  unsigned short* Vlds = (unsigned short*)smem;        // [128][512] bf16 = 128KB
  float* p_lds = (float*)(smem + 131072);              // [128]
  float* qbuf = (float*)(smem + 131584);               // [512]
  float* obuf = (float*)(smem + 133632);               // [4][512]

  const int b = blockIdx.x;
  const int tid = threadIdx.x;
  const int lane = tid & 63, w = tid >> 6;  // 16 waves

  if (tid < 512) {
    const int e = tid;
    const float* gib = gi + (size_t)b * E3;
    const float* ghb = gh + (size_t)b * E3;
    float ir = gib[e] + b_ih[e];
    float iz = gib[512 + e] + b_ih[512 + e];
    float inn = gib[1024 + e] + b_ih[1024 + e];
    float hr = ghb[e] + b_hh[e];
    float hz = ghb[512 + e] + b_hh[512 + e];
    float hn = ghb[1024 + e] + b_hh[1024 + e];
    float r = 1.f / (1.f + __expf(-(ir + hr)));
    float z = 1.f / (1.f + __expf(-(iz + hz)));
    float n = tanhf(inn + r * hn);
    float hp = h0[(size_t)b * Ee + e];
    float hnew = (1.f - z) * n + z * hp;
    out_h[(size_t)b * Ee + e] = hnew;
    in2f[IN2F_IDX(b, e)] = (unsigned short)f2bf(hnew);
    qbuf[e] = hnew;
  }

#define GATHER_B(T)                                                          \
  {                                                                          \
    const unsigned short* Tb = tabB + (size_t)(T) * ((size_t)Vv * Ee);       \
    _Pragma("unroll 2")                                                      \
    for (int r8 = 0; r8 < 8; ++r8) {                                         \
      const int row = w * 8 + r8;                                            \
      const int4 cc = *(const int4*)(ctx + ((size_t)b * Mm + row) * 4);      \
      uint4 va = *(const uint4*)(Tb + (size_t)cc.x * Ee + lane * 8);         \
      uint4 vb = *(const uint4*)(Tb + (size_t)cc.y * Ee + lane * 8);         \
      uint4 vc = *(const uint4*)(Tb + (size_t)cc.z * Ee + lane * 8);         \
      uint4 vd = *(const uint4*)(Tb + (size_t)cc.w * Ee + lane * 8);         \
      const unsigned int* pa = (const unsigned int*)&va;                     \
      const unsigned int* pb = (const unsigned int*)&vb;                     \
      const unsigned int* pc = (const unsigned int*)&vc;                     \
      const unsigned int* pd = (const unsigned int*)&vd;                     \
      unsigned int o[4];                                                     \
      _Pragma("unroll")                                                      \
      for (int j = 0; j < 4; ++j) {                                          \
        float lo = bf2f((unsigned short)(pa[j] & 0xffff)) +                  \
                   bf2f((unsigned short)(pb[j] & 0xffff)) +                  \
                   bf2f((unsigned short)(pc[j] & 0xffff)) +                  \
                   bf2f((unsigned short)(pd[j] & 0xffff));                   \
        float hi = bf2f((unsigned short)(pa[j] >> 16)) +                     \
                   bf2f((unsigned short)(pb[j] >> 16)) +                     \
                   bf2f((unsigned short)(pc[j] >> 16)) +                     \
                   bf2f((unsigned short)(pd[j] >> 16));                      \
        o[j] = f2bf(lo) | (f2bf(hi) << 16);                                  \
      }                                                                      \
      *(uint4*)(Vlds + (size_t)row * Ee + lane * 8) = *(uint4*)o;            \
    }                                                                        \
  }

#define GATHER_F(TAB)                                                        \
  {                                                                          \
    _Pragma("unroll 2")                                                      \
    for (int r8 = 0; r8 < 8; ++r8) {                                         \
      const int row = w * 8 + r8;                                            \
      const int4 cc = *(const int4*)(ctx + ((size_t)b * Mm + row) * 4);      \
      const float* s0 = TAB + (size_t)cc.x * Ee + lane * 8;                  \
      const float* s1 = TAB + (size_t)cc.y * Ee + lane * 8;                  \
      const float* s2 = TAB + (size_t)cc.z * Ee + lane * 8;                  \
      const float* s3 = TAB + (size_t)cc.w * Ee + lane * 8;                  \
      float4 a0 = *(const float4*)s0, a1 = *(const float4*)(s0 + 4);         \
      float4 b0 = *(const float4*)s1, b1 = *(const float4*)(s1 + 4);         \
      float4 c0 = *(const float4*)s2, c1 = *(const float4*)(s2 + 4);         \
      float4 d0 = *(const float4*)s3, d1 = *(const float4*)(s3 + 4);         \
      unsigned int o[4];                                                     \
      o[0] = f2bf(a0.x + b0.x + c0.x + d0.x) |                               \
             (f2bf(a0.y + b0.y + c0.y + d0.y) << 16);                        \
      o[1] = f2bf(a0.z + b0.z + c0.z + d0.z) |                               \
             (f2bf(a0.w + b0.w + c0.w + d0.w) << 16);                        \
      o[2] = f2bf(a1.x + b1.x + c1.x + d1.x) |                               \
             (f2bf(a1.y + b1.y + c1.y + d1.y) << 16);                        \
      o[3] = f2bf(a1.z + b1.z + c1.z + d1.z) |                               \
             (f2bf(a1.w + b1.w + c1.w + d1.w) << 16);                        \
      *(uint4*)(Vlds + (size_t)row * Ee + lane * 8) = *(uint4*)o;            \
    }                                                                        \
  }

#define GATHER(T, TAB) { if (tabB) GATHER_B(T) else GATHER_F(TAB) }

#define SCORE_PHASE(EMIT)                                                    \
  {                                                                          \
    float qf[8];                                                             \
    *(float4*)&qf[0] = *(const float4*)&qbuf[lane * 8];                      \
    *(float4*)&qf[4] = *(const float4*)&qbuf[lane * 8 + 4];                  \
    _Pragma("unroll")                                                        \
    for (int r = 0; r < 8; ++r) {                                            \
      const int m = w * 8 + r;                                               \
      uint4 kv = *(const uint4*)(Vlds + (size_t)m * Ee + lane * 8);          \
      const unsigned int* p4 = (const unsigned int*)&kv;                     \
      float s = 0.f;                                                         \
      _Pragma("unroll")                                                      \
      for (int x = 0; x < 4; ++x) {                                          \
        s += bf2f((unsigned short)(p4[x] & 0xffff)) * qf[2 * x];             \
        s += bf2f((unsigned short)(p4[x] >> 16)) * qf[2 * x + 1];            \
      }                                                                      \
      _Pragma("unroll")                                                      \
      for (int off = 32; off > 0; off >>= 1) s += __shfl_down(s, off);       \
      if (lane == 0) { EMIT; }                                               \
    }                                                                        \
  }

#define SOFTMAX_PHASE                                                        \
  if (tid < 64) {                                                            \
    float v0 = p_lds[tid], v1 = p_lds[tid + 64];                             \
    float mx = fmaxf(v0, v1);                                                \
    _Pragma("unroll")                                                        \
    for (int off = 32; off > 0; off >>= 1) mx = fmaxf(mx, __shfl_xor(mx, off)); \
    float e0 = __expf(v0 - mx), e1 = __expf(v1 - mx);                        \
    float s = e0 + e1;                                                       \
    _Pragma("unroll")                                                        \
    for (int off = 32; off > 0; off >>= 1) s += __shfl_xor(s, off);          \
    float inv = 1.f / s;                                                     \
    p_lds[tid] = e0 * inv;                                                   \
    p_lds[tid + 64] = e1 * inv;                                              \
  }

#define O_PHASE                                                              \
  {                                                                          \
    const int g = tid >> 8, t = tid & 255;                                   \
    const int e2 = t * 2;                                                    \
    float a0 = 0.f, a1 = 0.f;                                                \
    _Pragma("unroll 4")                                                      \
    for (int m = g * 32; m < g * 32 + 32; ++m) {                             \
      unsigned int vv = *(const unsigned int*)(Vlds + (size_t)m * Ee + e2);  \
      float ww = p_lds[m];                                                   \
      a0 += ww * bf2f((unsigned short)(vv & 0xffff));                        \
      a1 += ww * bf2f((unsigned short)(vv >> 16));                           \
    }                                                                        \
    obuf[g * 512 + e2] = a0;                                                 \
    obuf[g * 512 + e2 + 1] = a1;                                             \
  }

  // ---- hop 0
  GATHER(0, A0)
  __syncthreads();
  SCORE_PHASE(p_lds[m] = s)
  __syncthreads();
  SOFTMAX_PHASE
  GATHER(1, A1)
  __syncthreads();
  O_PHASE
  __syncthreads();
  if (tid < 512) {
    const int e = tid;
    float o = obuf[e] + obuf[512 + e] + obuf[1024 + e] + obuf[1536 + e];
    qbuf[e] = qbuf[e] + o;
    in2f[IN2F_IDX(b, 512 + e)] = (unsigned short)f2bf(o);
  }
  __syncthreads();

  // ---- hop 1
  SCORE_PHASE(p_lds[m] = s)
  __syncthreads();
  SOFTMAX_PHASE
  GATHER(2, A2)
  __syncthreads();
  O_PHASE
  __syncthreads();
  if (tid < 512) {
    const int e = tid;
    qbuf[e] = qbuf[e] + obuf[e] + obuf[512 + e] + obuf[1024 + e] + obuf[1536 + e];
  }
  __syncthreads();

  // ---- hop 2
  SCORE_PHASE(p_out[b * Mm + m] = s)
}

// p_vocab = in2f(bf16, fragment-order) @ lin_W^T + lin_b.
// R16's verified structure (A: 32x1KB units/k-tile through LDS; W: reg-dbuf ->
// (u+r)&7-swizzled LDS; one __syncthreads/iter; grid 500 N-only, W-once)
// re-partitioned for 1024 thr / 16 waves: wave (wm=w>>2, wn=w&3) owns a
// 64-row x 16-col quadrant (acc=16 VGPR), stages 2 A-units + 1 W-float4/tile.
// Same LDS (80KB), same traffic; launch_bounds(1024,8) caps VGPR at 64 so
// 2 blocks co-reside -> 32 waves/CU (TLP test on the fast LDS-staged path).
__global__ __launch_bounds__(1024, 8) void pvocab_kernel(
    const unsigned short* __restrict__ in2f,
    const float* __restrict__ lin_W,
    const float* __restrict__ lin_b,
    float* __restrict__ out_pv) {
  extern __shared__ char pvsmem[];
  unsigned short (*Ws)[64][64] = (unsigned short(*)[64][64])pvsmem;            // [2][64][64] 16KB
  unsigned short (*Al)[32][512] = (unsigned short(*)[32][512])(pvsmem + 16384); // [2][32][512] 64KB

  const int v0 = blockIdx.x * 64;
  const int tid = threadIdx.x;
  const int lane = tid & 63, w = tid >> 6;
  const int wm = w >> 2, wn = w & 3;        // 4 M-quarters x 4 N-quarters
  const int l15 = lane & 15, lg = lane >> 4;

  const int wrow = tid >> 4, wc4 = tid & 15;  // W-stage: row 0..63, float4 col

  f32x4 acc[4];
#pragma unroll
  for (int i = 0; i < 4; ++i) acc[i] = (f32x4){0.f, 0.f, 0.f, 0.f};

  float4 wR;
  uint4 aR[2];

#define PV_STAGE_LOAD(T)                                                     \
  {                                                                          \
    wR = *(const float4*)(lin_W + (size_t)(v0 + wrow) * 1024 + (T) * 64 + wc4 * 4); \
    _Pragma("unroll")                                                        \
    for (int it = 0; it < 2; ++it) {                                         \
      int u = w + it * 16;                     /* unit 0..31 */              \
      int mblk = u >> 1, kb = 2 * (T) + (u & 1);                             \
      aR[it] = *(const uint4*)(in2f + ((size_t)(mblk * 32 + kb)) * 512 + lane * 8); \
    }                                                                        \
  }

#define PV_STAGE_WRITE(BUF)                                                  \
  {                                                                          \
    unsigned int o0 = f2bf(wR.x) | (f2bf(wR.y) << 16);                       \
    unsigned int o1 = f2bf(wR.z) | (f2bf(wR.w) << 16);                       \
    int u = wc4 >> 1, h = wc4 & 1;                                           \
    *(uint2*)(&Ws[BUF][wrow][((u + wrow) & 7) * 8 + h * 4]) = make_uint2(o0, o1); \
    _Pragma("unroll")                                                        \
    for (int it = 0; it < 2; ++it) {                                         \
      int uu = w + it * 16;                                                  \
      *(uint4*)(&Al[BUF][uu][lane * 8]) = aR[it];                            \
    }                                                                        \
  }

  PV_STAGE_LOAD(0)
  PV_STAGE_WRITE(0)
  __syncthreads();

  int cur = 0;
  for (int t = 0; t < 16; ++t) {
    if (t + 1 < 16) PV_STAGE_LOAD(t + 1)   // W+A loads in flight under MFMA
#pragma unroll
    for (int kk = 0; kk < 2; ++kk) {
      const int cu = kk * 4 + lg;
      bf16x8 wf, af[4];
      {
        int row = wn * 16 + l15;
        wf = *(const bf16x8*)(&Ws[cur][row][((cu + row) & 7) * 8]);
      }
#pragma unroll
      for (int i = 0; i < 4; ++i)
        af[i] = *(const bf16x8*)(&Al[cur][(wm * 4 + i) * 2 + kk][lane * 8]);
#pragma unroll
      for (int i = 0; i < 4; ++i)
        acc[i] = __builtin_amdgcn_mfma_f32_16x16x32_bf16(af[i], wf, acc[i], 0, 0, 0);
    }
    if (t + 1 < 16) {
      PV_STAGE_WRITE(cur ^ 1)
      __syncthreads();
      cur ^= 1;
    }
  }

  {
    int v = v0 + wn * 16 + l15;
    float bias = lin_b[v];
#pragma unroll
    for (int i = 0; i < 4; ++i) {
      int brow = wm * 64 + i * 16 + lg * 4;
#pragma unroll
      for (int rr = 0; rr < 4; ++rr)
        out_pv[(size_t)(brow + rr) * Vv + v] = acc[i][rr] + bias;
    }
  }
}

extern "C" void kernel_launch(void* const* d_in, const int* in_sizes, int n_in,
                              void* d_out, int out_size, void* d_ws, size_t ws_size,
                              hipStream_t stream) {
  const int* ctx = (const int*)d_in[0];
  const int* y = (const int*)d_in[1];
  const float* h0 = (const float*)d_in[2];
  const float* A0 = (const float*)d_in[3];
  const float* A1 = (const float*)d_in[4];
  const float* A2 = (const float*)d_in[5];
  // d_in[6] (C2) dead: memories[3] only feeds hop-2's o/q, which never reach an output
  const float* W_ih = (const float*)d_in[7];
  const float* W_hh = (const float*)d_in[8];
  const float* b_ih = (const float*)d_in[9];
  const float* b_hh = (const float*)d_in[10];
  const float* lin_W = (const float*)d_in[11];
  const float* lin_b = (const float*)d_in[12];

  const size_t tabBytes = (size_t)3 * Vv * Ee * 2;   // 98.3 MB
  const size_t giBytes = (size_t)Bb * E3 * 4;
  const size_t in2Bytes = (size_t)Bb * 1024 * 2;
  const bool bf16path = ws_size >= tabBytes + 2 * giBytes + in2Bytes;

  char* ws = (char*)d_ws;
  size_t off = 0;
  unsigned short* tabB = nullptr;
  if (bf16path) { tabB = (unsigned short*)ws; off += tabBytes; }
  float* gi = (float*)(ws + off); off += giBytes;
  float* gh = (float*)(ws + off); off += giBytes;
  unsigned short* in2f = (unsigned short*)(ws + off);

  float* out = (float*)d_out;
  float* p_ptr = out;                              // [B,M]
  float* p_voc = out + Bb * Mm;                    // [B,V]
  float* out_h = out + Bb * Mm + (size_t)Bb * Vv;  // [1,B,E]

  if (bf16path)
    convert_kernel<<<dim3(4096, 3), 256, 0, stream>>>(A0, A1, A2, tabB);
  gru_gemm_kernel<<<dim3(4, 24, 2), 256, 0, stream>>>(y, A1, h0, W_ih, W_hh, gi, gh);
  hipFuncSetAttribute((const void*)fused_kernel,
                      hipFuncAttributeMaxDynamicSharedMemorySize, 141824);
  fused_kernel<<<Bb, 1024, 141824, stream>>>(ctx, tabB, A0, A1, A2, gi, gh,
                                             b_ih, b_hh, h0, out_h, in2f, p_ptr);
  hipFuncSetAttribute((const void*)pvocab_kernel,
                      hipFuncAttributeMaxDynamicSharedMemorySize, 81920);
  pvocab_kernel<<<Vv / 64, 1024, 81920, stream>>>(in2f, lin_W, lin_b, p_voc);
}